// Round 2
// baseline (1228.526 us; speedup 1.0000x reference)
//
#include <hip/hip_runtime.h>

#define ND    20000
#define NPn   10000
#define Bsz   4096
#define DE    320000
#define PEe   160000
#define FEAT  3372

#define ENC_OFF  4096ull
#define DEC_OFF  1052672ull              /* 4096*257 */
#define FEAT_OFF 14864384ull             /* DEC_OFF + 4096*3372 */

typedef unsigned short u16;
typedef unsigned int   u32;
typedef __bf16 bf16x8 __attribute__((ext_vector_type(8)));
typedef float  f32x4  __attribute__((ext_vector_type(4)));

__device__ __forceinline__ float bf2f(u16 u) {
    u32 v = ((u32)u) << 16;
    return __builtin_bit_cast(float, v);
}
__device__ __forceinline__ u16 f2bf(float f) {
    u32 x = __builtin_bit_cast(u32, f);
    x += 0x7fffu + ((x >> 16) & 1u);
    return (u16)(x >> 16);
}
__device__ __forceinline__ float lrelu(float x) { return x > 0.f ? x : 0.01f * x; }

// flag-driven scalar load/store (wave-uniform flag)
__device__ __forceinline__ float ldv(const void* p, size_t i, int f32) {
    return f32 ? ((const float*)p)[i] : bf2f(((const u16*)p)[i]);
}
__device__ __forceinline__ void stv(void* p, size_t i, int f32, float v) {
    if (f32) ((float*)p)[i] = v; else ((u16*)p)[i] = f2bf(v);
}

// async global->LDS 16B (wave-uniform LDS base + lane*16; linear dest)
typedef __attribute__((address_space(1))) const void GASV;
typedef __attribute__((address_space(3))) void LASV;
__device__ __forceinline__ void gld16(const u16* g, u16* l) {
    __builtin_amdgcn_global_load_lds((GASV*)g, (LASV*)l, 16, 0, 0);
}

// ---------------------------------------------------------------------------
// dtype detect: d_edge_weight is uniform[0,1). fp32 -> low u16 of each word is
// random mantissa bits (>0x4200 with p=.74). bf16 pairs -> both halves <=0x3F80.
// ---------------------------------------------------------------------------
__global__ void detect_dtype(const u32* __restrict__ ew, int* __restrict__ flag)
{
    int t = threadIdx.x, bad = 0;
    for (int i = t; i < 256; i += 64)
        if ((ew[i] & 0xffffu) > 0x4200u) bad = 1;
    unsigned long long m = __ballot(bad);
    if (t == 0) *flag = (m != 0ull) ? 1 : 0;   // 1 = fp32 inputs
}

// ---------------------------------------------------------------------------
// W[K,N] -> Th[N,Kp], Tl[N,Kp]  (bf16 hi/lo split planes, zero K-pad)
// ---------------------------------------------------------------------------
__global__ __launch_bounds__(256) void transpose_split(const void* __restrict__ W,
                                                       u16* __restrict__ Th,
                                                       u16* __restrict__ Tl,
                                                       int K, int N, int Kp,
                                                       const int* __restrict__ flagp)
{
    const int f32 = *flagp;
    __shared__ float tile[32][33];
    const int k0 = blockIdx.x * 32, n0 = blockIdx.y * 32;
    const int tx = threadIdx.x & 31, ty = threadIdx.x >> 5;
    for (int i = 0; i < 4; ++i) {
        int k = k0 + ty + 8 * i, n = n0 + tx;
        float v = 0.f;
        if (k < K && n < N) v = ldv(W, (size_t)k * N + n, f32);
        tile[ty + 8 * i][tx] = v;
    }
    __syncthreads();
    for (int i = 0; i < 4; ++i) {
        int n = n0 + ty + 8 * i, k = k0 + tx;
        if (n < N && k < Kp) {
            float v = tile[tx][ty + 8 * i];
            u16 h = f2bf(v);
            Th[(size_t)n * Kp + k] = h;
            Tl[(size_t)n * Kp + k] = f2bf(v - bf2f(h));
        }
    }
}

// ---------------------------------------------------------------------------
// Graph prep
// ---------------------------------------------------------------------------
__global__ void deg_accum(const int* __restrict__ ei, const void* __restrict__ ew,
                          float* __restrict__ deg, int E, const int* __restrict__ flagp)
{
    const int f32 = *flagp;
    int e = blockIdx.x * blockDim.x + threadIdx.x;
    if (e >= E) return;
    atomicAdd(&deg[ei[E + e]], ldv(ew, e, f32));
}

__global__ void dinv_kernel(float* __restrict__ deg, int n)
{
    int i = blockIdx.x * blockDim.x + threadIdx.x;
    if (i >= n) return;
    deg[i] = rsqrtf(deg[i] + 1.0f);   // +1 self-loop; always > 0
}

__global__ void csr_count(const int* __restrict__ ei, int* __restrict__ cnt, int E)
{
    int e = blockIdx.x * blockDim.x + threadIdx.x;
    if (e >= E) return;
    atomicAdd(&cnt[ei[E + e]], 1);
}

__global__ __launch_bounds__(256) void scan_kernel(const int* __restrict__ cnt,
                                                   int* __restrict__ offs,
                                                   int* __restrict__ cur, int n)
{
    __shared__ int tot[256];
    __shared__ int pref[257];
    const int t = threadIdx.x;
    const int chunk = (n + 255) / 256;
    const int s0 = t * chunk;
    const int s1 = (s0 + chunk < n) ? (s0 + chunk) : n;
    int s = 0;
    for (int i = s0; i < s1; ++i) s += cnt[i];
    tot[t] = s;
    __syncthreads();
    if (t == 0) {
        int run = 0;
        for (int i = 0; i < 256; ++i) { pref[i] = run; run += tot[i]; }
        pref[256] = run;
    }
    __syncthreads();
    int run = pref[t];
    for (int i = s0; i < s1; ++i) { offs[i] = run; cur[i] = run; run += cnt[i]; }
    if (t == 255) offs[n] = pref[256];
}

__global__ void csr_fill(const int* __restrict__ ei, const void* __restrict__ ew,
                         int* __restrict__ cur, int* __restrict__ crow,
                         float* __restrict__ cw, int E, const int* __restrict__ flagp)
{
    const int f32 = *flagp;
    int e = blockIdx.x * blockDim.x + threadIdx.x;
    if (e >= E) return;
    int c = ei[E + e];
    int p = atomicAdd(&cur[c], 1);
    crow[p] = ei[e];
    cw[p]   = ldv(ew, e, f32);
}

// ---------------------------------------------------------------------------
// Per-batch-row aggregation of raw X (commutes with @W):
//   agg[b] = dinv[c]^2 * X[c] + sum_e dinv[r]*w*dinv[c] * X[r],  c = idx[b]
// Output: bf16 hi/lo split planes [B, ldo] (zero K-pad) -- full-fp32 split,
// identical numerics to splitting at GEMM stage time.
// ---------------------------------------------------------------------------
__global__ __launch_bounds__(256) void aggregate(const void* __restrict__ X, int ldx,
                                                 int ncols,
                                                 const int* __restrict__ bidx,
                                                 const float* __restrict__ dinv,
                                                 const int* __restrict__ offs,
                                                 const int* __restrict__ crow,
                                                 const float* __restrict__ cw,
                                                 const int* __restrict__ flagp,
                                                 u16* __restrict__ outH,
                                                 u16* __restrict__ outL, int ldo)
{
    const int f32 = *flagp;
    const int b = blockIdx.x, t = threadIdx.x;
    const int node = bidx[b];
    const int nch = ncols >> 2;            // ncols divisible by 4 (1024, 2812)
    const float dc = dinv[node];
    float acc[3][4];
#pragma unroll
    for (int i = 0; i < 3; ++i)
        for (int j = 0; j < 4; ++j) acc[i][j] = 0.f;

    {   // self loop (weight 1)
        const float sw = dc * dc;
        const size_t rb = (size_t)node * ldx;
#pragma unroll
        for (int i = 0; i < 3; ++i) {
            int c = t + 256 * i;
            if (c < nch) {
                float v[4];
                if (f32) {
                    float4 x = *(const float4*)((const float*)X + rb + 4 * c);
                    v[0] = x.x; v[1] = x.y; v[2] = x.z; v[3] = x.w;
                } else {
                    uint2 x = *(const uint2*)((const u16*)X + rb + 4 * c);
                    v[0] = bf2f((u16)(x.x & 0xffffu)); v[1] = bf2f((u16)(x.x >> 16));
                    v[2] = bf2f((u16)(x.y & 0xffffu)); v[3] = bf2f((u16)(x.y >> 16));
                }
                for (int j = 0; j < 4; ++j) acc[i][j] += v[j] * sw;
            }
        }
    }
    const int e1 = offs[node + 1];
    for (int e = offs[node]; e < e1; ++e) {
        const int r = crow[e];
        const float nrm = dinv[r] * cw[e] * dc;
        const size_t rb = (size_t)r * ldx;
#pragma unroll
        for (int i = 0; i < 3; ++i) {
            int c = t + 256 * i;
            if (c < nch) {
                float v[4];
                if (f32) {
                    float4 x = *(const float4*)((const float*)X + rb + 4 * c);
                    v[0] = x.x; v[1] = x.y; v[2] = x.z; v[3] = x.w;
                } else {
                    uint2 x = *(const uint2*)((const u16*)X + rb + 4 * c);
                    v[0] = bf2f((u16)(x.x & 0xffffu)); v[1] = bf2f((u16)(x.x >> 16));
                    v[2] = bf2f((u16)(x.y & 0xffffu)); v[3] = bf2f((u16)(x.y >> 16));
                }
                for (int j = 0; j < 4; ++j) acc[i][j] += v[j] * nrm;
            }
        }
    }
    const size_t ob = (size_t)b * ldo;
#pragma unroll
    for (int i = 0; i < 3; ++i) {
        int c = t + 256 * i;
        if (c < nch) {
            u16 h[4], l[4];
#pragma unroll
            for (int j = 0; j < 4; ++j) {
                h[j] = f2bf(acc[i][j]);
                l[j] = f2bf(acc[i][j] - bf2f(h[j]));
            }
            uint2 hv, lv;
            hv.x = (u32)h[0] | ((u32)h[1] << 16); hv.y = (u32)h[2] | ((u32)h[3] << 16);
            lv.x = (u32)l[0] | ((u32)l[1] << 16); lv.y = (u32)l[2] | ((u32)l[3] << 16);
            *(uint2*)(outH + ob + 4 * c) = hv;
            *(uint2*)(outL + ob + 4 * c) = lv;
        }
    }
    if (t == 0)
        for (int j = ncols; j < ldo; ++j) { outH[ob + j] = 0; outL[ob + j] = 0; }
}

// ---------------------------------------------------------------------------
// Plane GEMM: C[M,N] = (Ah+Al)[M,Kp] @ (Bh+Bl)[N,Kp]^T  (+bias, +leaky)
// 3-term: Ah*Bh + Ah*Bl + Al*Bh (~2^-16 rel). All operands pre-split planes.
// Staging: global_load_lds width=16 into linear [128][32] LDS tiles,
// double-buffered, next tile issued BEFORE MFMA phase (min 2-phase pipeline).
// Outputs: optional C (dtype region of d_out / flag-driven) and/or split
// planes Ch/Cl for the next GEMM's A operand.
// M must be a multiple of 128 (always 4096 here).
// ---------------------------------------------------------------------------
__global__ __launch_bounds__(512, 2) void gemm_planes(
        const u16* __restrict__ Ah, const u16* __restrict__ Al, int lda,
        const u16* __restrict__ Bh, const u16* __restrict__ Bl, int ldb,
        void* __restrict__ C, int cmode, unsigned long long c_off, int ldc,
        u16* __restrict__ Ch, u16* __restrict__ Cl, int ldcp,
        const void* __restrict__ bias, int M, int N, int Kp,
        int do_leaky, const int* __restrict__ flagp)
{
    const int flag = *flagp;
    const int cf32 = cmode ? flag : 1;
    __shared__ u16 smAh[2][128 * 32], smAl[2][128 * 32];
    __shared__ u16 smBh[2][128 * 32], smBl[2][128 * 32];
    const int tid = threadIdx.x;
    const int m0 = blockIdx.y * 128, n0 = blockIdx.x * 128;
    const int w = tid >> 6, lane = tid & 63;
    const int wy = w >> 1, wx = w & 1, lr = lane & 15, q = lane >> 4;
    f32x4 acc[2][4] = {};

    // staging map: thread t -> row t>>2, 16B slot t&3; LDS linear [128][32]u16
    const int sr = tid >> 2;
    const int sc = (tid & 3) * 8;
    const size_t gA = (size_t)(m0 + sr) * lda + sc;
    const size_t gB = (size_t)(n0 + sr) * ldb + sc;
    const int wb = w << 9;                  // wave LDS base (u16): w*64 lanes*16B

    auto stage = [&](int k0, int buf) {
        gld16(Ah + gA + k0, &smAh[buf][wb]);
        gld16(Al + gA + k0, &smAl[buf][wb]);
        gld16(Bh + gB + k0, &smBh[buf][wb]);
        gld16(Bl + gB + k0, &smBl[buf][wb]);
    };

    stage(0, 0);
    __syncthreads();
    int cur = 0;
    for (int k0 = 0; k0 < Kp; k0 += 32) {
        const int nxt = k0 + 32;
        if (nxt < Kp) stage(nxt, cur ^ 1);   // async, rides across MFMA phase
        bf16x8 bh[4], bl[4];
#pragma unroll
        for (int ni = 0; ni < 4; ++ni) {
            bh[ni] = *(const bf16x8*)&smBh[cur][(wx * 64 + ni * 16 + lr) * 32 + q * 8];
            bl[ni] = *(const bf16x8*)&smBl[cur][(wx * 64 + ni * 16 + lr) * 32 + q * 8];
        }
#pragma unroll
        for (int mi = 0; mi < 2; ++mi) {
            bf16x8 ah = *(const bf16x8*)&smAh[cur][(wy * 32 + mi * 16 + lr) * 32 + q * 8];
            bf16x8 al = *(const bf16x8*)&smAl[cur][(wy * 32 + mi * 16 + lr) * 32 + q * 8];
#pragma unroll
            for (int ni = 0; ni < 4; ++ni) {
                acc[mi][ni] = __builtin_amdgcn_mfma_f32_16x16x32_bf16(ah, bh[ni], acc[mi][ni], 0, 0, 0);
                acc[mi][ni] = __builtin_amdgcn_mfma_f32_16x16x32_bf16(ah, bl[ni], acc[mi][ni], 0, 0, 0);
                acc[mi][ni] = __builtin_amdgcn_mfma_f32_16x16x32_bf16(al, bh[ni], acc[mi][ni], 0, 0, 0);
            }
        }
        __syncthreads();                     // drains vmcnt+lgkmcnt, flips buffer
        cur ^= 1;
    }

    // ---- epilogue: C/D layout col=lane&15, row=(lane>>4)*4+reg ----
#pragma unroll
    for (int mi = 0; mi < 2; ++mi)
#pragma unroll
        for (int r = 0; r < 4; ++r) {
            const int gm = m0 + wy * 32 + mi * 16 + q * 4 + r;
#pragma unroll
            for (int ni = 0; ni < 4; ++ni) {
                const int gn = n0 + wx * 64 + ni * 16 + lr;
                if (gn >= N) continue;
                float v = acc[mi][ni][r];
                if (bias) v += ldv(bias, gn, flag);
                if (do_leaky) v = lrelu(v);
                float vq = v;
                if (C) {
                    const size_t ci = (size_t)c_off + (size_t)gm * ldc + gn;
                    if (cf32) ((float*)C)[ci] = v;
                    else { u16 hh = f2bf(v); ((u16*)C)[ci] = hh; vq = bf2f(hh); }
                }
                if (Ch) {
                    const size_t pi = (size_t)gm * ldcp + gn;
                    u16 h = f2bf(vq);
                    Ch[pi] = h;
                    Cl[pi] = f2bf(vq - bf2f(h));
                }
            }
        }
}

// ---------------------------------------------------------------------------
// feature cols [0,1324) = [d_vecs | p_embeddings] -> d_out + split planes;
// also zero-pads feature-plane cols [3372,3392).
// ---------------------------------------------------------------------------
__global__ __launch_bounds__(256) void concat(const void* __restrict__ d_vecs,
                                              const void* __restrict__ p_emb,
                                              void* __restrict__ out,
                                              u16* __restrict__ Fh,
                                              u16* __restrict__ Fl,
                                              const int* __restrict__ flagp)
{
    const int f32 = *flagp;
    const int b = blockIdx.x;
    const size_t fb = FEAT_OFF + (size_t)b * FEAT;
    const size_t pb = (size_t)b * 3392;
    for (int j = threadIdx.x; j < 1324; j += 256) {
        float v = (j < 300) ? ldv(d_vecs, (size_t)b * 300 + j, f32)
                            : ldv(p_emb, (size_t)b * 1024 + (j - 300), f32);
        stv(out, fb + j, f32, v);
        float vq = f32 ? v : bf2f(f2bf(v));
        u16 h = f2bf(vq);
        Fh[pb + j] = h;
        Fl[pb + j] = f2bf(vq - bf2f(h));
    }
    for (int j = 3372 + threadIdx.x; j < 3392; j += 256) {
        Fh[pb + j] = 0; Fl[pb + j] = 0;
    }
}

// ---------------------------------------------------------------------------
// Head: h = enc@W1+b1 -> BN(eval) -> leaky -> @W2+b2 -> y
// ---------------------------------------------------------------------------
__global__ __launch_bounds__(128) void head(void* __restrict__ out,
                                            const void* __restrict__ W1,
                                            const void* __restrict__ b1,
                                            const void* __restrict__ g,
                                            const void* __restrict__ be,
                                            const void* __restrict__ mu,
                                            const void* __restrict__ vr,
                                            const void* __restrict__ W2,
                                            const void* __restrict__ b2,
                                            const int* __restrict__ flagp)
{
    const int f32 = *flagp;
    __shared__ float se[256];
    __shared__ float red[128];
    const int b = blockIdx.x, t = threadIdx.x;
    const size_t eb = ENC_OFF + (size_t)b * 256;
    se[t]       = ldv(out, eb + t, f32);
    se[t + 128] = ldv(out, eb + 128 + t, f32);
    __syncthreads();
    float acc = 0.f;
    for (int k = 0; k < 256; ++k) acc += se[k] * ldv(W1, (size_t)k * 128 + t, f32);
    acc += ldv(b1, t, f32);
    float bn = (acc - ldv(mu, t, f32)) * rsqrtf(ldv(vr, t, f32) + 1e-5f) * ldv(g, t, f32)
             + ldv(be, t, f32);
    red[t] = lrelu(bn) * ldv(W2, t, f32);
    __syncthreads();
    for (int s = 64; s > 0; s >>= 1) {
        if (t < s) red[t] += red[t + s];
        __syncthreads();
    }
    if (t == 0) stv(out, (size_t)b, f32, red[0] + ldv(b2, 0, f32));
}

// ---------------------------------------------------------------------------
extern "C" void kernel_launch(void* const* d_in, const int* in_sizes, int n_in,
                              void* d_out, int out_size, void* d_ws, size_t ws_size,
                              hipStream_t stream)
{
    (void)in_sizes; (void)n_in; (void)out_size; (void)ws_size;

    const int*  d_index = (const int*)d_in[0];
    const int*  p_index = (const int*)d_in[1];
    const void* d_vecs  = d_in[2];
    const void* p_emb   = d_in[3];
    const void* d_ecfps = d_in[4];
    const int*  d_ei    = (const int*)d_in[5];
    const void* d_ew    = d_in[6];
    const void* p_gos   = d_in[7];
    const int*  p_ei    = (const int*)d_in[8];
    const void* p_ew    = d_in[9];
    const void* d_gcn_W = d_in[10];
    const void* d_gcn_b = d_in[11];
    const void* p_gcn_W = d_in[12];
    const void* p_gcn_b = d_in[13];
    const void* enc_W1  = d_in[14];
    const void* enc_b1  = d_in[15];
    const void* enc_W2  = d_in[16];
    const void* enc_b2  = d_in[17];
    const void* dec_W1  = d_in[18];
    const void* dec_b1  = d_in[19];
    const void* dec_W2  = d_in[20];
    const void* dec_b2  = d_in[21];
    const void* out_W1  = d_in[22];
    const void* out_b1  = d_in[23];
    const void* bn_g    = d_in[24];
    const void* bn_b    = d_in[25];
    const void* bn_m    = d_in[26];
    const void* bn_v    = d_in[27];
    const void* out_W2  = d_in[28];
    const void* out_b2  = d_in[29];

    // ---- workspace carve-up ----
    char* base = (char*)d_ws;
    size_t off = 0;
    auto alloc = [&](size_t bytes) -> void* {
        void* p = base + off;
        off = (off + bytes + 255) & ~(size_t)255;
        return p;
    };
    // B (weight) planes
    u16* Th_d  = (u16*)alloc((size_t)1024 * 1024 * 2);
    u16* Tl_d  = (u16*)alloc((size_t)1024 * 1024 * 2);
    u16* Th_p  = (u16*)alloc((size_t)1024 * 2816 * 2);
    u16* Tl_p  = (u16*)alloc((size_t)1024 * 2816 * 2);
    u16* Th_e1 = (u16*)alloc((size_t)1024 * 3392 * 2);
    u16* Tl_e1 = (u16*)alloc((size_t)1024 * 3392 * 2);
    u16* Th_e2 = (u16*)alloc((size_t)256  * 1024 * 2);
    u16* Tl_e2 = (u16*)alloc((size_t)256  * 1024 * 2);
    u16* Th_d1 = (u16*)alloc((size_t)1024 * 256  * 2);
    u16* Tl_d1 = (u16*)alloc((size_t)1024 * 256  * 2);
    u16* Th_d2 = (u16*)alloc((size_t)3456 * 1024 * 2);   // N padded to 3456 rows
    u16* Tl_d2 = (u16*)alloc((size_t)3456 * 1024 * 2);
    // A (activation) planes
    u16* AgDh = (u16*)alloc((size_t)Bsz * 1024 * 2);
    u16* AgDl = (u16*)alloc((size_t)Bsz * 1024 * 2);
    u16* AgPh = (u16*)alloc((size_t)Bsz * 2816 * 2);
    u16* AgPl = (u16*)alloc((size_t)Bsz * 2816 * 2);
    u16* Fh   = (u16*)alloc((size_t)Bsz * 3392 * 2);
    u16* Fl   = (u16*)alloc((size_t)Bsz * 3392 * 2);
    // aliases (lifetimes verified: producer runs strictly after last consumer)
    u16* E1h = AgDh;                         // enc1 out  (AgD dead after GCN-d)
    u16* E1l = AgDl;
    u16* Eh  = AgPh;                         // encoded   (AgP dead after GCN-p)
    u16* El  = AgPh + (size_t)Bsz * 256;
    u16* D1h = AgPl;                         // dec1 out
    u16* D1l = AgPl + (size_t)Bsz * 1024;
    // graph prep
    float* deg_d  = (float*)alloc((size_t)ND  * 4);
    float* deg_p  = (float*)alloc((size_t)NPn * 4);
    int*   cnt_d  = (int*)alloc((size_t)ND * 4);
    int*   offs_d = (int*)alloc((size_t)(ND + 1) * 4);
    int*   cur_d  = (int*)alloc((size_t)ND * 4);
    int*   cnt_p  = (int*)alloc((size_t)NPn * 4);
    int*   offs_p = (int*)alloc((size_t)(NPn + 1) * 4);
    int*   cur_p  = (int*)alloc((size_t)NPn * 4);
    int*   crow_d = (int*)alloc((size_t)DE * 4);
    float* cw_d   = (float*)alloc((size_t)DE * 4);
    int*   crow_p = (int*)alloc((size_t)PEe * 4);
    float* cw_p   = (float*)alloc((size_t)PEe * 4);
    int*   flagp  = (int*)alloc(16);

    // ---- init ----
    detect_dtype<<<1, 64, 0, stream>>>((const u32*)d_ew, flagp);
    hipMemsetAsync(deg_d, 0, (size_t)ND * 4, stream);
    hipMemsetAsync(deg_p, 0, (size_t)NPn * 4, stream);
    hipMemsetAsync(cnt_d, 0, (size_t)ND * 4, stream);
    hipMemsetAsync(cnt_p, 0, (size_t)NPn * 4, stream);

    // ---- weight transposes + hi/lo split ----
    transpose_split<<<dim3(32, 32),  256, 0, stream>>>(d_gcn_W, Th_d,  Tl_d,  1024, 1024, 1024, flagp);
    transpose_split<<<dim3(88, 32),  256, 0, stream>>>(p_gcn_W, Th_p,  Tl_p,  2812, 1024, 2816, flagp);
    transpose_split<<<dim3(106, 32), 256, 0, stream>>>(enc_W1,  Th_e1, Tl_e1, 3372, 1024, 3392, flagp);
    transpose_split<<<dim3(32, 8),   256, 0, stream>>>(enc_W2,  Th_e2, Tl_e2, 1024, 256,  1024, flagp);
    transpose_split<<<dim3(8, 32),   256, 0, stream>>>(dec_W1,  Th_d1, Tl_d1, 256,  1024, 256,  flagp);
    transpose_split<<<dim3(32, 106), 256, 0, stream>>>(dec_W2,  Th_d2, Tl_d2, 1024, 3372, 1024, flagp);

    // ---- graph prep ----
    deg_accum<<<(DE + 255) / 256, 256, 0, stream>>>(d_ei, d_ew, deg_d, DE, flagp);
    deg_accum<<<(PEe + 255) / 256, 256, 0, stream>>>(p_ei, p_ew, deg_p, PEe, flagp);
    dinv_kernel<<<(ND + 255) / 256, 256, 0, stream>>>(deg_d, ND);
    dinv_kernel<<<(NPn + 255) / 256, 256, 0, stream>>>(deg_p, NPn);
    csr_count<<<(DE + 255) / 256, 256, 0, stream>>>(d_ei, cnt_d, DE);
    csr_count<<<(PEe + 255) / 256, 256, 0, stream>>>(p_ei, cnt_p, PEe);
    scan_kernel<<<1, 256, 0, stream>>>(cnt_d, offs_d, cur_d, ND);
    scan_kernel<<<1, 256, 0, stream>>>(cnt_p, offs_p, cur_p, NPn);
    csr_fill<<<(DE + 255) / 256, 256, 0, stream>>>(d_ei, d_ew, cur_d, crow_d, cw_d, DE, flagp);
    csr_fill<<<(PEe + 255) / 256, 256, 0, stream>>>(p_ei, p_ew, cur_p, crow_p, cw_p, PEe, flagp);

    // ---- aggregate raw X per batch row -> split planes ----
    aggregate<<<Bsz, 256, 0, stream>>>(d_ecfps, 1024, 1024, d_index, deg_d,
                                       offs_d, crow_d, cw_d, flagp, AgDh, AgDl, 1024);
    aggregate<<<Bsz, 256, 0, stream>>>(p_gos, 2812, 2812, p_index, deg_p,
                                       offs_p, crow_p, cw_p, flagp, AgPh, AgPl, 2816);

    // ---- GCN linears (d_out feature cols + feature planes) ----
    gemm_planes<<<dim3(8, 32), 512, 0, stream>>>(AgDh, AgDl, 1024, Th_d, Tl_d, 1024,
                                                 d_out, 1, FEAT_OFF + 1324, FEAT,
                                                 Fh + 1324, Fl + 1324, 3392,
                                                 d_gcn_b, Bsz, 1024, 1024, 1, flagp);
    gemm_planes<<<dim3(8, 32), 512, 0, stream>>>(AgPh, AgPl, 2816, Th_p, Tl_p, 2816,
                                                 d_out, 1, FEAT_OFF + 2348, FEAT,
                                                 Fh + 2348, Fl + 2348, 3392,
                                                 p_gcn_b, Bsz, 1024, 2816, 1, flagp);

    // ---- feature cols [0,1324) + plane tail pad ----
    concat<<<Bsz, 256, 0, stream>>>(d_vecs, p_emb, d_out, Fh, Fl, flagp);

    // ---- encoder / decoder ----
    gemm_planes<<<dim3(8, 32), 512, 0, stream>>>(Fh, Fl, 3392, Th_e1, Tl_e1, 3392,
                                                 nullptr, 0, 0, 0,
                                                 E1h, E1l, 1024,
                                                 enc_b1, Bsz, 1024, 3392, 1, flagp);
    gemm_planes<<<dim3(2, 32), 512, 0, stream>>>(E1h, E1l, 1024, Th_e2, Tl_e2, 1024,
                                                 d_out, 1, ENC_OFF, 256,
                                                 Eh, El, 256,
                                                 enc_b2, Bsz, 256, 1024, 1, flagp);
    gemm_planes<<<dim3(8, 32), 512, 0, stream>>>(Eh, El, 256, Th_d1, Tl_d1, 256,
                                                 nullptr, 0, 0, 0,
                                                 D1h, D1l, 1024,
                                                 dec_b1, Bsz, 1024, 256, 1, flagp);
    gemm_planes<<<dim3(27, 32), 512, 0, stream>>>(D1h, D1l, 1024, Th_d2, Tl_d2, 1024,
                                                  d_out, 1, DEC_OFF, FEAT,
                                                  nullptr, nullptr, 0,
                                                  dec_b2, Bsz, 3372, 1024, 1, flagp);

    // ---- head ----
    head<<<Bsz, 128, 0, stream>>>(d_out, out_W1, out_b1, bn_g, bn_b,
                                  bn_m, bn_v, out_W2, out_b2, flagp);
}